// Round 3
// baseline (549.013 us; speedup 1.0000x reference)
//
#include <hip/hip_runtime.h>
#include <cstdint>
#include <cstddef>

#define T_TOK 4096
#define DM 1024
#define HS 4096
#define NE 8
#define MAXROWS 9216   // 8192 pairs + 8*128 padding worst case
#define MAXTILES 72    // MAXROWS/128

typedef __attribute__((ext_vector_type(8))) short short8;
typedef __attribute__((ext_vector_type(4))) float floatx4;

__device__ __forceinline__ unsigned short f2bf(float f) {
  union { float f; unsigned u; } v; v.f = f;
  unsigned r = (v.u + 0x7fffu + ((v.u >> 16) & 1u)) >> 16;
  return (unsigned short)r;
}

__device__ __forceinline__ unsigned pack2bf(float a, float b) {
  return (unsigned)f2bf(a) | ((unsigned)f2bf(b) << 16);
}

__device__ __forceinline__ void gload_lds16(const void* g, void* l) {
  __builtin_amdgcn_global_load_lds((const __attribute__((address_space(1))) void*)g,
                                   (__attribute__((address_space(3))) void*)l, 16, 0, 0);
}

// ---------------- small kernels ----------------

__global__ void k_init(int* counts, int* cursor, unsigned* list) {
  int i = blockIdx.x * 256 + threadIdx.x;
  if (i < NE) { counts[i] = 0; cursor[i] = 0; }
  if (i < MAXROWS) list[i] = 0xFFFFFFFFu;
}

__global__ void k_route(const float* __restrict__ x, const float* __restrict__ rw,
                        const float* __restrict__ rb, const float* __restrict__ lw,
                        const float* __restrict__ lb, int* __restrict__ top_i,
                        float* __restrict__ top_p, int* __restrict__ counts) {
  int t = blockIdx.x * 4 + (threadIdx.x >> 6);
  int lane = threadIdx.x & 63;
  const float4* xt = (const float4*)(x + (size_t)t * DM);
  float4 xv[4];
#pragma unroll
  for (int j = 0; j < 4; j++) xv[j] = xt[lane * 4 + j];
  float dots[12];
#pragma unroll
  for (int r = 0; r < 12; r++) {
    const float4* wr = (const float4*)(r < 4 ? lw + r * DM : rw + (r - 4) * DM);
    float s = 0.f;
#pragma unroll
    for (int j = 0; j < 4; j++) {
      float4 w = wr[lane * 4 + j];
      s += xv[j].x * w.x + xv[j].y * w.y + xv[j].z * w.z + xv[j].w * w.w;
    }
#pragma unroll
    for (int o = 32; o > 0; o >>= 1) s += __shfl_xor(s, o, 64);
    dots[r] = s;
  }
  if (lane == 0) {
    float lp[4]; float m = -1e30f;
#pragma unroll
    for (int i = 0; i < 4; i++) { lp[i] = dots[i] + lb[i]; m = fmaxf(m, lp[i]); }
    float sum = 0.f;
#pragma unroll
    for (int i = 0; i < 4; i++) { lp[i] = expf(lp[i] - m); sum += lp[i]; }
#pragma unroll
    for (int i = 0; i < 4; i++) lp[i] /= sum;
    float ew[4];
    ew[0] = lp[0] + lp[1]; ew[1] = lp[1] + lp[2]; ew[2] = lp[2] + lp[3]; ew[3] = lp[3];
    float r8[8];
#pragma unroll
    for (int e = 0; e < 8; e++) r8[e] = dots[4 + e] + rb[e] + 0.1f * ew[e & 3];
    int e0 = 0;
#pragma unroll
    for (int e = 1; e < 8; e++) if (r8[e] > r8[e0]) e0 = e;
    int e1 = (e0 == 0) ? 1 : 0;
#pragma unroll
    for (int e = 0; e < 8; e++) if (e != e0 && r8[e] > r8[e1]) e1 = e;
    float tt = expf(r8[e1] - r8[e0]);
    float w0 = 1.f / (1.f + tt);
    float w1 = tt / (1.f + tt);
    top_i[t * 2] = e0; top_i[t * 2 + 1] = e1;
    top_p[t * 2] = w0; top_p[t * 2 + 1] = w1;
    atomicAdd(&counts[e0], 1); atomicAdd(&counts[e1], 1);
  }
}

__global__ void k_offsets(const int* counts, int* off) {
  if (threadIdx.x == 0) {
    int acc = 0;
    for (int e = 0; e < NE; e++) {
      off[e] = acc;
      int p = ((counts[e] + 127) >> 7) << 7;
      acc += p;
    }
    off[NE] = acc;
  }
}

__global__ void k_scatter(const int* __restrict__ top_i, const int* __restrict__ off,
                          int* cursor, unsigned* __restrict__ list) {
  int t = blockIdx.x * 256 + threadIdx.x;
  if (t >= T_TOK) return;
#pragma unroll
  for (int k = 0; k < 2; k++) {
    int e = top_i[t * 2 + k];
    int pos = atomicAdd(&cursor[e], 1);
    list[off[e] + pos] = (unsigned)(t * 2 + k);
  }
}

__global__ void k_cvt_x(const float* __restrict__ x, unsigned short* __restrict__ xb) {
  int i = blockIdx.x * 256 + threadIdx.x;  // 4 elems per thread
  float4 v = ((const float4*)x)[i];
  union { unsigned short us[4]; uint2 u2; } o;
  o.us[0] = f2bf(v.x); o.us[1] = f2bf(v.y); o.us[2] = f2bf(v.z); o.us[3] = f2bf(v.w);
  ((uint2*)xb)[i] = o.u2;
}

__global__ void k_init_out(const int* __restrict__ top_i, const float* __restrict__ top_p,
                           const float* __restrict__ b2, float* __restrict__ out) {
  int i = blockIdx.x * 256 + threadIdx.x;
  int t = i >> 10, d = i & 1023;
  int e0 = top_i[t * 2], e1 = top_i[t * 2 + 1];
  out[i] = top_p[t * 2] * b2[e0 * DM + d] + top_p[t * 2 + 1] * b2[e1 * DM + d];
}

// ---------------- grouped GEMM ----------------
// 128x128 tile, BK=32, double-buffered LDS, single barrier per K-step.
// A (tokens/h, bf16): global_load_lds with source-chunk swizzle.
// B (weights): read NATIVE f32 [E][K][N] layout -> regs (coalesced float2
//   column loads), cvt to bf16 in-register, ds_write_b128 into the same
//   XOR-swizzled LDS layout the fragment reads use. No transpose kernels.
// MODE 0: h = gelu(xg @ w1 + b1)   (A gathered via list)   C bf16 -> Hout
// MODE 1: out += p * (h @ w2)      (A linear rows)          atomicAdd f32
template <int MODE, int K, int N>
__global__ __launch_bounds__(256, 2) void k_gemm(
    const unsigned short* __restrict__ Abase,
    const float* __restrict__ W,     // [E][K][N] f32 native
    const int* __restrict__ off, const unsigned* __restrict__ list,
    const float* __restrict__ bias, const float* __restrict__ top_p,
    unsigned short* __restrict__ Hout, float* __restrict__ out) {
  // XCD-aware chunked swizzle on flat block id (nwg % 8 == 0 for both grids)
  int nx = gridDim.x;
  int flat = blockIdx.y * nx + blockIdx.x;
  int cpx = (nx * gridDim.y) >> 3;
  int swz = (flat & 7) * cpx + (flat >> 3);
  int n0 = (swz % nx) * 128;
  int r0 = (swz / nx) * 128;

  int total = off[NE];
  if (r0 >= total) return;
  int e = 0;
  while (r0 >= off[e + 1]) ++e;

  __shared__ __align__(16) unsigned short lA[2][128 * 32];
  __shared__ __align__(16) unsigned short lB[2][128 * 32];
  __shared__ float sP[128];
  __shared__ int sTok[128];

  int tid = threadIdx.x;
  // ---- A staging (global_load_lds, rule-21: linear dest + inv-swizzled src) ----
  int srow = tid >> 2;                 // 0..63 (row within 64-row half)
  int key_s = (srow >> 1) & 3;
  int koff_src = ((tid & 3) ^ key_s) * 8;   // bf16 elems: swizzled source chunk
  int kdst = (tid & 3) * 8;                 // linear LDS dest chunk

  const unsigned short* srcA[2];
#pragma unroll
  for (int c = 0; c < 2; c++) {
    int row = c * 64 + srow;
    size_t arow;
    if (MODE == 0) {
      unsigned pair = list[r0 + row];
      arow = (pair == 0xFFFFFFFFu) ? 0 : (size_t)(pair >> 1);
    } else {
      arow = (size_t)(r0 + row);
    }
    srcA[c] = Abase + arow * K + koff_src;
  }

  // ---- B reg-staging setup: thread covers rows n=bn,bn+1, k-chunk bq ----
  int bq = tid >> 6;                    // k-chunk 0..3 (k = bq*8 .. bq*8+7)
  int bn = (tid & 63) * 2;              // n within tile (even)
  const float* pB = W + (size_t)e * K * N + (size_t)(bq * 8) * N + n0 + bn;
  int pc = (bq ^ ((bn >> 1) & 3)) * 8;  // physical chunk (elem offset), same key as reads

  if (MODE == 1 && tid < 128) {
    unsigned pair = list[r0 + tid];
    if (pair == 0xFFFFFFFFu) { sTok[tid] = -1; sP[tid] = 0.f; }
    else { sTok[tid] = (int)(pair >> 1); sP[tid] = top_p[pair]; }
  }

  floatx4 acc[4][4] = {};
  int lane = tid & 63;
  int w = tid >> 6;
  int wm = w >> 1, wn = w & 1;
  int lr = lane & 15, kq = lane >> 4;
  int kx = kq ^ ((lr >> 1) & 3);        // swizzled 16B-chunk slot for reads

  float2 rb[8];

#define ALOAD(BUF, KK)                                                        \
  do {                                                                        \
    _Pragma("unroll")                                                         \
    for (int c = 0; c < 2; c++)                                               \
      gload_lds16(srcA[c] + (KK), &lA[BUF][(c * 64 + srow) * 32 + kdst]);     \
  } while (0)

#define BLOAD(KK)                                                             \
  do {                                                                        \
    const float* p_ = pB + (size_t)(KK) * N;                                  \
    _Pragma("unroll")                                                         \
    for (int j = 0; j < 8; j++) rb[j] = *(const float2*)(p_ + (size_t)j * N); \
  } while (0)

#define BWRITE(BUF)                                                           \
  do {                                                                        \
    uint4 q0, q1;                                                             \
    q0.x = pack2bf(rb[0].x, rb[1].x); q0.y = pack2bf(rb[2].x, rb[3].x);       \
    q0.z = pack2bf(rb[4].x, rb[5].x); q0.w = pack2bf(rb[6].x, rb[7].x);       \
    q1.x = pack2bf(rb[0].y, rb[1].y); q1.y = pack2bf(rb[2].y, rb[3].y);       \
    q1.z = pack2bf(rb[4].y, rb[5].y); q1.w = pack2bf(rb[6].y, rb[7].y);       \
    *(uint4*)&lB[BUF][bn * 32 + pc] = q0;                                     \
    *(uint4*)&lB[BUF][(bn + 1) * 32 + pc] = q1;                               \
  } while (0)

  // prologue: stage tile 0
  ALOAD(0, 0);
  BLOAD(0);
  BWRITE(0);
  __syncthreads();

  int cur = 0;
  for (int k0 = 0; k0 < K; k0 += 32) {
    if (k0 + 32 < K) {
      ALOAD(cur ^ 1, k0 + 32);   // in flight across the MFMA block
      BLOAD(k0 + 32);            // in flight across the MFMA block
    }
    const short8* pAf = (const short8*)lA[cur];
    const short8* pBf = (const short8*)lB[cur];
    short8 a[4], b[4];
#pragma unroll
    for (int i = 0; i < 4; i++) a[i] = pAf[(wm * 64 + i * 16 + lr) * 4 + kx];
#pragma unroll
    for (int j = 0; j < 4; j++) b[j] = pBf[(wn * 64 + j * 16 + lr) * 4 + kx];
#pragma unroll
    for (int i = 0; i < 4; i++)
#pragma unroll
      for (int j = 0; j < 4; j++)
        acc[i][j] = __builtin_amdgcn_mfma_f32_16x16x32_bf16(a[i], b[j], acc[i][j], 0, 0, 0);
    if (k0 + 32 < K) BWRITE(cur ^ 1);  // cvt (waits B regs) + LDS write, post-MFMA
    __syncthreads();                   // RAW fence for cur^1; WAR covered by prev barrier
    cur ^= 1;
  }
#undef ALOAD
#undef BLOAD
#undef BWRITE

  int rbase = wm * 64 + kq * 4;
  int cbase = wn * 64 + lr;
  if (MODE == 0) {
#pragma unroll
    for (int i = 0; i < 4; i++)
#pragma unroll
      for (int j = 0; j < 4; j++)
#pragma unroll
        for (int g = 0; g < 4; g++) {
          int row = rbase + i * 16 + g;
          int col = cbase + j * 16;
          float v = acc[i][j][g] + bias[e * N + n0 + col];
          v = 0.5f * v * (1.f + erff(v * 0.70710678118f));
          Hout[(size_t)(r0 + row) * (size_t)N + n0 + col] = f2bf(v);
        }
  } else {
#pragma unroll
    for (int i = 0; i < 4; i++)
#pragma unroll
      for (int j = 0; j < 4; j++)
#pragma unroll
        for (int g = 0; g < 4; g++) {
          int row = rbase + i * 16 + g;
          int col = cbase + j * 16;
          int tok = sTok[row];
          if (tok >= 0)
            atomicAdd(&out[(size_t)tok * DM + n0 + col], sP[row] * acc[i][j][g]);
        }
  }
}

// ---------------- launch ----------------

extern "C" void kernel_launch(void* const* d_in, const int* in_sizes, int n_in,
                              void* d_out, int out_size, void* d_ws, size_t ws_size,
                              hipStream_t stream) {
  const float* x  = (const float*)d_in[0];
  const float* rw = (const float*)d_in[1];
  const float* rb = (const float*)d_in[2];
  const float* lw = (const float*)d_in[3];
  const float* lb = (const float*)d_in[4];
  const float* w1 = (const float*)d_in[5];
  const float* b1 = (const float*)d_in[6];
  const float* w2 = (const float*)d_in[7];
  const float* b2 = (const float*)d_in[8];
  float* out = (float*)d_out;
  char* ws = (char*)d_ws;

  int* counts = (int*)ws;
  int* cursor = (int*)(ws + 32);
  int* off    = (int*)(ws + 64);
  int* top_i  = (int*)(ws + 128);
  float* top_p = (float*)(ws + 128 + 32768);
  unsigned* list = (unsigned*)(ws + 65792);
  unsigned short* xb = (unsigned short*)(ws + 102912);                 // 8 MB
  unsigned short* h  = (unsigned short*)(ws + 102912 + 8388608);       // 75.5 MB

  k_init<<<dim3((MAXROWS + 255) / 256), dim3(256), 0, stream>>>(counts, cursor, list);
  k_route<<<dim3(T_TOK / 4), dim3(256), 0, stream>>>(x, rw, rb, lw, lb, top_i, top_p, counts);
  k_offsets<<<dim3(1), dim3(64), 0, stream>>>(counts, off);
  k_scatter<<<dim3(T_TOK / 256), dim3(256), 0, stream>>>(top_i, off, cursor, list);
  k_cvt_x<<<dim3(T_TOK * DM / 4 / 256), dim3(256), 0, stream>>>(x, xb);
  k_init_out<<<dim3(T_TOK * DM / 256), dim3(256), 0, stream>>>(top_i, top_p, b2, out);
  k_gemm<0, DM, HS><<<dim3(HS / 128, MAXTILES), dim3(256), 0, stream>>>(
      xb, w1, off, list, b1, top_p, h, nullptr);
  k_gemm<1, HS, DM><<<dim3(DM / 128, MAXTILES), dim3(256), 0, stream>>>(
      h, w2, off, list, nullptr, top_p, nullptr, out);
}

// Round 4
// 541.492 us; speedup vs baseline: 1.0139x; 1.0139x over previous
//
#include <hip/hip_runtime.h>
#include <cstdint>
#include <cstddef>

#define T_TOK 4096
#define DM 1024
#define HS 4096
#define NE 8
#define MAXROWS 9216   // 8192 pairs + 8*128 padding worst case
#define MAXTILES 72    // MAXROWS/128

typedef __attribute__((ext_vector_type(8))) short short8;
typedef __attribute__((ext_vector_type(4))) float floatx4;

__device__ __forceinline__ unsigned short f2bf(float f) {
  union { float f; unsigned u; } v; v.f = f;
  unsigned r = (v.u + 0x7fffu + ((v.u >> 16) & 1u)) >> 16;
  return (unsigned short)r;
}

__device__ __forceinline__ void gload_lds16(const void* g, void* l) {
  __builtin_amdgcn_global_load_lds((const __attribute__((address_space(1))) void*)g,
                                   (__attribute__((address_space(3))) void*)l, 16, 0, 0);
}

// ---------------- small kernels ----------------

// x f32 -> bf16, fused with routing-metadata init (saves a launch)
__global__ void k_cvt_init(const float* __restrict__ x, unsigned short* __restrict__ xb,
                           int* counts, int* cursor, unsigned* list) {
  int i = blockIdx.x * 256 + threadIdx.x;  // 4 elems per thread
  if (i < NE) { counts[i] = 0; cursor[i] = 0; }
  if (i < MAXROWS) list[i] = 0xFFFFFFFFu;
  float4 v = ((const float4*)x)[i];
  union { unsigned short us[4]; uint2 u2; } o;
  o.us[0] = f2bf(v.x); o.us[1] = f2bf(v.y); o.us[2] = f2bf(v.z); o.us[3] = f2bf(v.w);
  ((uint2*)xb)[i] = o.u2;
}

__global__ void k_route(const float* __restrict__ x, const float* __restrict__ rw,
                        const float* __restrict__ rb, const float* __restrict__ lw,
                        const float* __restrict__ lb, int* __restrict__ top_i,
                        float* __restrict__ top_p, int* __restrict__ counts) {
  int t = blockIdx.x * 4 + (threadIdx.x >> 6);
  int lane = threadIdx.x & 63;
  const float4* xt = (const float4*)(x + (size_t)t * DM);
  float4 xv[4];
#pragma unroll
  for (int j = 0; j < 4; j++) xv[j] = xt[lane * 4 + j];
  float dots[12];
#pragma unroll
  for (int r = 0; r < 12; r++) {
    const float4* wr = (const float4*)(r < 4 ? lw + r * DM : rw + (r - 4) * DM);
    float s = 0.f;
#pragma unroll
    for (int j = 0; j < 4; j++) {
      float4 w = wr[lane * 4 + j];
      s += xv[j].x * w.x + xv[j].y * w.y + xv[j].z * w.z + xv[j].w * w.w;
    }
#pragma unroll
    for (int o = 32; o > 0; o >>= 1) s += __shfl_xor(s, o, 64);
    dots[r] = s;
  }
  if (lane == 0) {
    float lp[4]; float m = -1e30f;
#pragma unroll
    for (int i = 0; i < 4; i++) { lp[i] = dots[i] + lb[i]; m = fmaxf(m, lp[i]); }
    float sum = 0.f;
#pragma unroll
    for (int i = 0; i < 4; i++) { lp[i] = expf(lp[i] - m); sum += lp[i]; }
#pragma unroll
    for (int i = 0; i < 4; i++) lp[i] /= sum;
    float ew[4];
    ew[0] = lp[0] + lp[1]; ew[1] = lp[1] + lp[2]; ew[2] = lp[2] + lp[3]; ew[3] = lp[3];
    float r8[8];
#pragma unroll
    for (int e = 0; e < 8; e++) r8[e] = dots[4 + e] + rb[e] + 0.1f * ew[e & 3];
    int e0 = 0;
#pragma unroll
    for (int e = 1; e < 8; e++) if (r8[e] > r8[e0]) e0 = e;
    int e1 = (e0 == 0) ? 1 : 0;
#pragma unroll
    for (int e = 0; e < 8; e++) if (e != e0 && r8[e] > r8[e1]) e1 = e;
    float tt = expf(r8[e1] - r8[e0]);
    float w0 = 1.f / (1.f + tt);
    float w1 = tt / (1.f + tt);
    top_i[t * 2] = e0; top_i[t * 2 + 1] = e1;
    top_p[t * 2] = w0; top_p[t * 2 + 1] = w1;
    atomicAdd(&counts[e0], 1); atomicAdd(&counts[e1], 1);
  }
}

__global__ void k_offsets(const int* counts, int* off) {
  if (threadIdx.x == 0) {
    int acc = 0;
    for (int e = 0; e < NE; e++) {
      off[e] = acc;
      int p = ((counts[e] + 127) >> 7) << 7;
      acc += p;
    }
    off[NE] = acc;
  }
}

__global__ void k_scatter(const int* __restrict__ top_i, const int* __restrict__ off,
                          int* cursor, unsigned* __restrict__ list) {
  int t = blockIdx.x * 256 + threadIdx.x;
  if (t >= T_TOK) return;
#pragma unroll
  for (int k = 0; k < 2; k++) {
    int e = top_i[t * 2 + k];
    int pos = atomicAdd(&cursor[e], 1);
    list[off[e] + pos] = (unsigned)(t * 2 + k);
  }
}

// transpose+convert: src f32 [e][K][N] -> dst bf16 [e][N][K]
__global__ void k_transpose_bf16(const float* __restrict__ src, unsigned short* __restrict__ dst,
                                 int K, int N) {
  __shared__ float tile[64][65];
  const float* s = src + (size_t)blockIdx.z * K * N;
  unsigned short* d = dst + (size_t)blockIdx.z * K * N;
  int n0 = blockIdx.x * 64, k0 = blockIdx.y * 64;
  int tr = threadIdx.x >> 4;          // 0..15
  int tc = (threadIdx.x & 15) * 4;    // 0,4,...,60
#pragma unroll
  for (int j = 0; j < 4; j++) {
    int row = tr + j * 16;
    float4 v = *(const float4*)&s[(size_t)(k0 + row) * N + n0 + tc];
    tile[row][tc + 0] = v.x; tile[row][tc + 1] = v.y;
    tile[row][tc + 2] = v.z; tile[row][tc + 3] = v.w;
  }
  __syncthreads();
#pragma unroll
  for (int j = 0; j < 4; j++) {
    int n = tr + j * 16;
    union { unsigned short us[4]; uint2 u2; } o;
#pragma unroll
    for (int i = 0; i < 4; i++) o.us[i] = f2bf(tile[tc + i][n]);
    *(uint2*)&d[(size_t)(n0 + n) * K + k0 + tc] = o.u2;
  }
}

__global__ void k_init_out(const int* __restrict__ top_i, const float* __restrict__ top_p,
                           const float* __restrict__ b2, float* __restrict__ out) {
  int i = blockIdx.x * 256 + threadIdx.x;
  int t = i >> 10, d = i & 1023;
  int e0 = top_i[t * 2], e1 = top_i[t * 2 + 1];
  out[i] = top_p[t * 2] * b2[e0 * DM + d] + top_p[t * 2 + 1] * b2[e1 * DM + d];
}

// ---------------- grouped GEMM ----------------
// 128x128 tile, BK=32, RING-3 LDS + counted vmcnt: loads for tile t+2 stay in
// flight across the tile-boundary barrier (only tile t+1 must be complete ->
// s_waitcnt vmcnt(4)). Never drains vmcnt to 0 in the main loop.
// 2 sub-phases per tile: {stage A(t+2) || 8 MFMA}, {stage B(t+2) || 8 MFMA},
// setprio(1) around MFMA clusters. 48KB LDS -> 3 blocks/CU.
// MODE 0: h = gelu(xg @ w1t^T + b1)  (A gathered via list)   C bf16 -> Hout
// MODE 1: out += p * (h @ w2t^T)     (A linear rows, split-K) atomicAdd f32
template <int MODE, int K, int N, int KT>
__global__ __launch_bounds__(256, 3) void k_gemm(
    const unsigned short* __restrict__ Abase,
    const unsigned short* __restrict__ Wt,   // [E][N][K] bf16
    const int* __restrict__ off, const unsigned* __restrict__ list,
    const float* __restrict__ bias, const float* __restrict__ top_p,
    unsigned short* __restrict__ Hout, float* __restrict__ out) {
  // XCD-aware chunked swizzle on flat block id (nwg % 8 == 0 for both grids)
  int gx = gridDim.x, gy = gridDim.y;
  int flat = (blockIdx.z * gy + blockIdx.y) * gx + blockIdx.x;
  int nwg = gx * gy * gridDim.z;
  int cpx = nwg >> 3;
  int swz = (flat & 7) * cpx + (flat >> 3);
  int bn = swz % gx; int rest = swz / gx;
  int bm = rest % gy; int zz = rest / gy;
  int n0 = bn * 128;
  int r0 = bm * 128;
  int kb = zz * (KT * 32);            // split-K base (elements)

  int total = off[NE];
  if (r0 >= total) return;
  int e = 0;
  while (r0 >= off[e + 1]) ++e;

  __shared__ __align__(16) unsigned short lA[3][128 * 32];
  __shared__ __align__(16) unsigned short lB[3][128 * 32];
  __shared__ float sP[128];
  __shared__ int sTok[128];

  int tid = threadIdx.x;
  int srow = tid >> 2;                 // 0..63 (row within 64-row half)
  int skey = (srow >> 1) & 3;
  int koff_src = ((tid & 3) ^ skey) * 8;   // swizzled source chunk (rule 21)
  int ldst = srow * 32 + (tid & 3) * 8;    // linear LDS dest

  const unsigned short* srcA[2];
#pragma unroll
  for (int c = 0; c < 2; c++) {
    int row = c * 64 + srow;
    size_t arow;
    if (MODE == 0) {
      unsigned pair = list[r0 + row];
      arow = (pair == 0xFFFFFFFFu) ? 0 : (size_t)(pair >> 1);
    } else {
      arow = (size_t)(r0 + row);
    }
    srcA[c] = Abase + arow * K + kb + koff_src;
  }
  const unsigned short* srcB[2];
#pragma unroll
  for (int c = 0; c < 2; c++)
    srcB[c] = Wt + ((size_t)e * N + n0 + c * 64 + srow) * K + kb + koff_src;

  if (MODE == 1 && tid < 128) {
    unsigned pair = list[r0 + tid];
    if (pair == 0xFFFFFFFFu) { sTok[tid] = -1; sP[tid] = 0.f; }
    else { sTok[tid] = (int)(pair >> 1); sP[tid] = top_p[pair]; }
  }

  floatx4 acc[4][4] = {};
  int lane = tid & 63;
  int w = tid >> 6;
  int wm = w >> 1, wn = w & 1;
  int lr = lane & 15, kq = lane >> 4;
  int kx = kq ^ ((lr >> 1) & 3);       // swizzled 16B-chunk slot for reads
  int aBase = (wm * 64 + lr) * 4 + kx; // short8 index; + m*64
  int bBase = (wn * 64 + lr) * 4 + kx; // + n*64

#define STAGE_A(BUF, TT)                                                      \
  do {                                                                        \
    _Pragma("unroll")                                                         \
    for (int c = 0; c < 2; c++)                                               \
      gload_lds16(srcA[c] + (size_t)(TT) * 32, &lA[BUF][c * 2048 + ldst]);    \
  } while (0)
#define STAGE_B(BUF, TT)                                                      \
  do {                                                                        \
    _Pragma("unroll")                                                         \
    for (int c = 0; c < 2; c++)                                               \
      gload_lds16(srcB[c] + (size_t)(TT) * 32, &lB[BUF][c * 2048 + ldst]);    \
  } while (0)

  // drain sTok/list/top_p loads BEFORE staging so vmcnt counting stays exact;
  // also publishes sTok/sP LDS writes.
  __syncthreads();

  // prologue: stage tiles 0 and 1 (8 loads/thread)
  STAGE_A(0, 0); STAGE_B(0, 0);
  STAGE_A(1, 1); STAGE_B(1, 1);
  asm volatile("s_waitcnt vmcnt(4)\ns_barrier" ::: "memory");  // tile 0 ready

  int cur = 0, nxt = 2;
  for (int t = 0; t < KT; ++t) {
    const short8* pA = (const short8*)lA[cur];
    const short8* pB = (const short8*)lB[cur];
    bool pf = (t + 2 < KT);
    // ---- phase 0: stage A(t+2), compute n-half 0 ----
    if (pf) STAGE_A(nxt, t + 2);
    short8 a0[4], b0[2];
#pragma unroll
    for (int m = 0; m < 4; m++) a0[m] = pA[aBase + m * 64];
#pragma unroll
    for (int n = 0; n < 2; n++) b0[n] = pB[bBase + n * 64];
    __builtin_amdgcn_s_setprio(1);
#pragma unroll
    for (int m = 0; m < 4; m++)
#pragma unroll
      for (int n = 0; n < 2; n++)
        acc[m][n] = __builtin_amdgcn_mfma_f32_16x16x32_bf16(a0[m], b0[n], acc[m][n], 0, 0, 0);
    __builtin_amdgcn_s_setprio(0);
    // ---- phase 1: stage B(t+2), compute n-half 1 ----
    if (pf) STAGE_B(nxt, t + 2);
    short8 b1v[2];
#pragma unroll
    for (int n = 0; n < 2; n++) b1v[n] = pB[bBase + (n + 2) * 64];
    __builtin_amdgcn_s_setprio(1);
#pragma unroll
    for (int m = 0; m < 4; m++)
#pragma unroll
      for (int n = 0; n < 2; n++)
        acc[m][n + 2] = __builtin_amdgcn_mfma_f32_16x16x32_bf16(a0[m], b1v[n], acc[m][n + 2], 0, 0, 0);
    __builtin_amdgcn_s_setprio(0);
    // ---- boundary: wait only for tile t+1 (4 loads may stay in flight) ----
    if (t + 1 < KT) {
      if (pf) asm volatile("s_waitcnt vmcnt(4)\ns_barrier" ::: "memory");
      else    asm volatile("s_waitcnt vmcnt(0)\ns_barrier" ::: "memory");
    }
    cur = (cur == 2) ? 0 : cur + 1;
    nxt = (nxt == 2) ? 0 : nxt + 1;
  }
#undef STAGE_A
#undef STAGE_B

  int rbase = wm * 64 + kq * 4;
  int cbase = wn * 64 + lr;
  if (MODE == 0) {
#pragma unroll
    for (int i = 0; i < 4; i++)
#pragma unroll
      for (int j = 0; j < 4; j++)
#pragma unroll
        for (int g = 0; g < 4; g++) {
          int row = rbase + i * 16 + g;
          int col = cbase + j * 16;
          float v = acc[i][j][g] + bias[e * N + n0 + col];
          // tanh-GELU (max abs err ~3e-4, well inside bf16 margin), ~3x cheaper than erff
          float u = v * (0.7978845608f + 0.0356774081f * v * v);
          float gl = v / (1.f + __expf(-2.f * u));
          Hout[(size_t)(r0 + row) * (size_t)N + n0 + col] = f2bf(gl);
        }
  } else {
#pragma unroll
    for (int i = 0; i < 4; i++)
#pragma unroll
      for (int j = 0; j < 4; j++)
#pragma unroll
        for (int g = 0; g < 4; g++) {
          int row = rbase + i * 16 + g;
          int col = cbase + j * 16;
          int tok = sTok[row];
          if (tok >= 0)
            atomicAdd(&out[(size_t)tok * DM + n0 + col], sP[row] * acc[i][j][g]);
        }
  }
}

// ---------------- launch ----------------

extern "C" void kernel_launch(void* const* d_in, const int* in_sizes, int n_in,
                              void* d_out, int out_size, void* d_ws, size_t ws_size,
                              hipStream_t stream) {
  const float* x  = (const float*)d_in[0];
  const float* rw = (const float*)d_in[1];
  const float* rb = (const float*)d_in[2];
  const float* lw = (const float*)d_in[3];
  const float* lb = (const float*)d_in[4];
  const float* w1 = (const float*)d_in[5];
  const float* b1 = (const float*)d_in[6];
  const float* w2 = (const float*)d_in[7];
  const float* b2 = (const float*)d_in[8];
  float* out = (float*)d_out;
  char* ws = (char*)d_ws;

  int* counts = (int*)ws;
  int* cursor = (int*)(ws + 32);
  int* off    = (int*)(ws + 64);
  int* top_i  = (int*)(ws + 128);
  float* top_p = (float*)(ws + 128 + 32768);
  unsigned* list = (unsigned*)(ws + 65792);
  unsigned short* xb = (unsigned short*)(ws + 102912);
  unsigned short* wt = (unsigned short*)(ws + 102912 + 8388608);            // 64 MB shared w1t/w2t
  unsigned short* h  = (unsigned short*)(ws + 102912 + 8388608 + 67108864); // 72 MB

  k_cvt_init<<<dim3(T_TOK * DM / 4 / 256), dim3(256), 0, stream>>>(x, xb, counts, cursor, list);
  k_route<<<dim3(T_TOK / 4), dim3(256), 0, stream>>>(x, rw, rb, lw, lb, top_i, top_p, counts);
  k_offsets<<<dim3(1), dim3(64), 0, stream>>>(counts, off);
  k_scatter<<<dim3(T_TOK / 256), dim3(256), 0, stream>>>(top_i, off, cursor, list);
  k_transpose_bf16<<<dim3(HS / 64, DM / 64, NE), dim3(256), 0, stream>>>(w1, wt, DM, HS);
  k_init_out<<<dim3(T_TOK * DM / 256), dim3(256), 0, stream>>>(top_i, top_p, b2, out);
  k_gemm<0, DM, HS, DM / 32><<<dim3(HS / 128, MAXTILES, 1), dim3(256), 0, stream>>>(
      xb, wt, off, list, b1, top_p, h, nullptr);
  k_transpose_bf16<<<dim3(DM / 64, HS / 64, NE), dim3(256), 0, stream>>>(w2, wt, HS, DM);
  k_gemm<1, HS, DM, HS / 4 / 32><<<dim3(DM / 128, MAXTILES, 4), dim3(256), 0, stream>>>(
      h, wt, off, list, nullptr, top_p, nullptr, out);
}

// Round 5
// 531.173 us; speedup vs baseline: 1.0336x; 1.0194x over previous
//
#include <hip/hip_runtime.h>
#include <cstdint>
#include <cstddef>

#define T_TOK 4096
#define DM 1024
#define HS 4096
#define NE 8
#define MAXROWS 10240  // 8192 pairs + 8*256 padding worst case
#define MAXTILES 40    // MAXROWS/256

typedef __attribute__((ext_vector_type(8))) short short8;
typedef __attribute__((ext_vector_type(4))) float floatx4;

__device__ __forceinline__ unsigned short f2bf(float f) {
  union { float f; unsigned u; } v; v.f = f;
  unsigned r = (v.u + 0x7fffu + ((v.u >> 16) & 1u)) >> 16;
  return (unsigned short)r;
}

__device__ __forceinline__ void gload_lds16(const void* g, void* l) {
  __builtin_amdgcn_global_load_lds((const __attribute__((address_space(1))) void*)g,
                                   (__attribute__((address_space(3))) void*)l, 16, 0, 0);
}

// ---------------- small kernels ----------------

// x f32 -> bf16, fused with routing-metadata init
__global__ void k_cvt_init(const float* __restrict__ x, unsigned short* __restrict__ xb,
                           int* counts, int* cursor, unsigned* list) {
  int i = blockIdx.x * 256 + threadIdx.x;  // 4 elems per thread
  if (i < NE) { counts[i] = 0; cursor[i] = 0; }
  if (i < MAXROWS) list[i] = 0xFFFFFFFFu;
  float4 v = ((const float4*)x)[i];
  union { unsigned short us[4]; uint2 u2; } o;
  o.us[0] = f2bf(v.x); o.us[1] = f2bf(v.y); o.us[2] = f2bf(v.z); o.us[3] = f2bf(v.w);
  ((uint2*)xb)[i] = o.u2;
}

__global__ void k_route(const float* __restrict__ x, const float* __restrict__ rw,
                        const float* __restrict__ rb, const float* __restrict__ lw,
                        const float* __restrict__ lb, int* __restrict__ top_i,
                        float* __restrict__ top_p, int* __restrict__ counts) {
  int t = blockIdx.x * 4 + (threadIdx.x >> 6);
  int lane = threadIdx.x & 63;
  const float4* xt = (const float4*)(x + (size_t)t * DM);
  float4 xv[4];
#pragma unroll
  for (int j = 0; j < 4; j++) xv[j] = xt[lane * 4 + j];
  float dots[12];
#pragma unroll
  for (int r = 0; r < 12; r++) {
    const float4* wr = (const float4*)(r < 4 ? lw + r * DM : rw + (r - 4) * DM);
    float s = 0.f;
#pragma unroll
    for (int j = 0; j < 4; j++) {
      float4 w = wr[lane * 4 + j];
      s += xv[j].x * w.x + xv[j].y * w.y + xv[j].z * w.z + xv[j].w * w.w;
    }
#pragma unroll
    for (int o = 32; o > 0; o >>= 1) s += __shfl_xor(s, o, 64);
    dots[r] = s;
  }
  if (lane == 0) {
    float lp[4]; float m = -1e30f;
#pragma unroll
    for (int i = 0; i < 4; i++) { lp[i] = dots[i] + lb[i]; m = fmaxf(m, lp[i]); }
    float sum = 0.f;
#pragma unroll
    for (int i = 0; i < 4; i++) { lp[i] = expf(lp[i] - m); sum += lp[i]; }
#pragma unroll
    for (int i = 0; i < 4; i++) lp[i] /= sum;
    float ew[4];
    ew[0] = lp[0] + lp[1]; ew[1] = lp[1] + lp[2]; ew[2] = lp[2] + lp[3]; ew[3] = lp[3];
    float r8[8];
#pragma unroll
    for (int e = 0; e < 8; e++) r8[e] = dots[4 + e] + rb[e] + 0.1f * ew[e & 3];
    int e0 = 0;
#pragma unroll
    for (int e = 1; e < 8; e++) if (r8[e] > r8[e0]) e0 = e;
    int e1 = (e0 == 0) ? 1 : 0;
#pragma unroll
    for (int e = 0; e < 8; e++) if (e != e0 && r8[e] > r8[e1]) e1 = e;
    float tt = expf(r8[e1] - r8[e0]);
    float w0 = 1.f / (1.f + tt);
    float w1 = tt / (1.f + tt);
    top_i[t * 2] = e0; top_i[t * 2 + 1] = e1;
    top_p[t * 2] = w0; top_p[t * 2 + 1] = w1;
    atomicAdd(&counts[e0], 1); atomicAdd(&counts[e1], 1);
  }
}

__global__ void k_offsets(const int* counts, int* off) {
  if (threadIdx.x == 0) {
    int acc = 0;
    for (int e = 0; e < NE; e++) {
      off[e] = acc;
      int p = ((counts[e] + 255) >> 8) << 8;   // pad to 256 (tile M)
      acc += p;
    }
    off[NE] = acc;
  }
}

__global__ void k_scatter(const int* __restrict__ top_i, const int* __restrict__ off,
                          int* cursor, unsigned* __restrict__ list) {
  int t = blockIdx.x * 256 + threadIdx.x;
  if (t >= T_TOK) return;
#pragma unroll
  for (int k = 0; k < 2; k++) {
    int e = top_i[t * 2 + k];
    int pos = atomicAdd(&cursor[e], 1);
    list[off[e] + pos] = (unsigned)(t * 2 + k);
  }
}

// transpose+convert: src f32 [e][K][N] -> dst bf16 [e][N][K]
__global__ void k_transpose_bf16(const float* __restrict__ src, unsigned short* __restrict__ dst,
                                 int K, int N) {
  __shared__ float tile[64][65];
  const float* s = src + (size_t)blockIdx.z * K * N;
  unsigned short* d = dst + (size_t)blockIdx.z * K * N;
  int n0 = blockIdx.x * 64, k0 = blockIdx.y * 64;
  int tr = threadIdx.x >> 4;          // 0..15
  int tc = (threadIdx.x & 15) * 4;    // 0,4,...,60
#pragma unroll
  for (int j = 0; j < 4; j++) {
    int row = tr + j * 16;
    float4 v = *(const float4*)&s[(size_t)(k0 + row) * N + n0 + tc];
    tile[row][tc + 0] = v.x; tile[row][tc + 1] = v.y;
    tile[row][tc + 2] = v.z; tile[row][tc + 3] = v.w;
  }
  __syncthreads();
#pragma unroll
  for (int j = 0; j < 4; j++) {
    int n = tr + j * 16;
    union { unsigned short us[4]; uint2 u2; } o;
#pragma unroll
    for (int i = 0; i < 4; i++) o.us[i] = f2bf(tile[tc + i][n]);
    *(uint2*)&d[(size_t)(n0 + n) * K + k0 + tc] = o.u2;
  }
}

__global__ void k_init_out(const int* __restrict__ top_i, const float* __restrict__ top_p,
                           const float* __restrict__ b2, float* __restrict__ out) {
  int i = blockIdx.x * 256 + threadIdx.x;
  int t = i >> 10, d = i & 1023;
  int e0 = top_i[t * 2], e1 = top_i[t * 2 + 1];
  out[i] = top_p[t * 2] * b2[e0 * DM + d] + top_p[t * 2 + 1] * b2[e1 * DM + d];
}

// ---------------- grouped GEMM: 256x256 tile, BK=64, 512 threads ----------------
// 8 waves (2M x 4N), per-wave 128x64 output, acc[8][4]. LDS 128KB dbuf, 1 blk/CU.
// Step: {ds_read kk0 frags; issue 8 gload_lds(t+1); 32 MFMA; ds_read kk1; 32 MFMA;
//        s_waitcnt vmcnt(0); s_barrier}. 3-bit XOR chunk swizzle (row&7).
// MODE 0: h = gelu(xg @ w1t^T + b1)  (A gathered)            C bf16 -> Hout
// MODE 1: out += p * (h @ w2t^T)     (A linear, split-K)     atomicAdd f32
template <int MODE, int K, int N, int KT>
__global__ __launch_bounds__(512, 1) void k_gemm(
    const unsigned short* __restrict__ Abase,
    const unsigned short* __restrict__ Wt,   // [E][N][K] bf16
    const int* __restrict__ off, const unsigned* __restrict__ list,
    const float* __restrict__ bias, const float* __restrict__ top_p,
    unsigned short* __restrict__ Hout, float* __restrict__ out) {
  int gx = gridDim.x, gy = gridDim.y;
  int flat = (blockIdx.z * gy + blockIdx.y) * gx + blockIdx.x;
  int nwg = gx * gy * gridDim.z;
  int cpx = nwg >> 3;
  int swz = (flat & 7) * cpx + (flat >> 3);
  int bn = swz % gx; int rest = swz / gx;
  int bm = rest % gy; int z = rest / gy;
  int n0 = bn * 256, r0 = bm * 256;
  int kb = z * (KT * 64);
  int total = off[NE];
  if (r0 >= total) return;
  int e = 0;
  while (r0 >= off[e + 1]) ++e;

  __shared__ __align__(16) unsigned short lA[2][256 * 64];
  __shared__ __align__(16) unsigned short lB[2][256 * 64];
  __shared__ float sP[256];
  __shared__ int sTok[256];

  int tid = threadIdx.x;
  int w = tid >> 6, lane = tid & 63;
  int g8 = lane >> 3, c8 = lane & 7;     // staging: row-in-group, phys chunk
  int rowS = w * 8 + g8;                 // base row (load l adds l*64)
  int koff = (c8 ^ g8) * 8;              // swizzled source k-elem offset (key=row&7=g8)

  unsigned aOff[4], bOff[4];
#pragma unroll
  for (int l = 0; l < 4; l++) {
    int rowA = l * 64 + rowS;
    unsigned arow;
    if (MODE == 0) {
      unsigned pair = list[r0 + rowA];
      arow = (pair == 0xFFFFFFFFu) ? 0u : (pair >> 1);
    } else {
      arow = (unsigned)(r0 + rowA);
    }
    aOff[l] = arow * (unsigned)K + (unsigned)(kb + koff);
    bOff[l] = (unsigned)(e * N + n0 + rowA) * (unsigned)K + (unsigned)(kb + koff);
  }
  int ldsb = rowS * 64 + c8 * 8;         // ushort idx; load l adds l*4096

  if (MODE == 1 && tid < 256) {
    unsigned pair = list[r0 + tid];
    if (pair == 0xFFFFFFFFu) { sTok[tid] = -1; sP[tid] = 0.f; }
    else { sTok[tid] = (int)(pair >> 1); sP[tid] = top_p[pair]; }
  }

  // fragment geometry
  int wm = w >> 2, wn = w & 3;
  int lr = lane & 15, kq = lane >> 4;
  int rsel = (lr & 7);                   // read-side swizzle key

  floatx4 acc[8][4] = {};

#define STAGE(BUF, TT)                                                        \
  do {                                                                        \
    _Pragma("unroll")                                                         \
    for (int l = 0; l < 4; l++)                                               \
      gload_lds16(Abase + aOff[l] + (TT) * 64, &lA[BUF][l * 4096 + ldsb]);    \
    _Pragma("unroll")                                                         \
    for (int l = 0; l < 4; l++)                                               \
      gload_lds16(Wt + bOff[l] + (TT) * 64, &lB[BUF][l * 4096 + ldsb]);       \
  } while (0)

  __syncthreads();  // publish sTok/sP; drain metadata loads
  STAGE(0, 0);
  asm volatile("s_waitcnt vmcnt(0)" ::: "memory");
  __builtin_amdgcn_s_barrier();

  int cur = 0;
  for (int t = 0; t < KT; ++t) {
    const short8* qA = (const short8*)lA[cur];
    const short8* qB = (const short8*)lB[cur];
    // ---- kk = 0: ds_read frags FIRST, then issue next-tile staging ----
    short8 a[8], b[4];
#pragma unroll
    for (int m = 0; m < 8; m++)
      a[m] = qA[(wm * 128 + m * 16 + lr) * 8 + ((0 * 4 + kq) ^ rsel)];
#pragma unroll
    for (int n = 0; n < 4; n++)
      b[n] = qB[(wn * 64 + n * 16 + lr) * 8 + ((0 * 4 + kq) ^ rsel)];
    if (t + 1 < KT) STAGE(cur ^ 1, t + 1);
    __builtin_amdgcn_s_setprio(1);
#pragma unroll
    for (int m = 0; m < 8; m++)
#pragma unroll
      for (int n = 0; n < 4; n++)
        acc[m][n] = __builtin_amdgcn_mfma_f32_16x16x32_bf16(a[m], b[n], acc[m][n], 0, 0, 0);
    __builtin_amdgcn_s_setprio(0);
    // ---- kk = 1 ----
#pragma unroll
    for (int m = 0; m < 8; m++)
      a[m] = qA[(wm * 128 + m * 16 + lr) * 8 + ((1 * 4 + kq) ^ rsel)];
#pragma unroll
    for (int n = 0; n < 4; n++)
      b[n] = qB[(wn * 64 + n * 16 + lr) * 8 + ((1 * 4 + kq) ^ rsel)];
    __builtin_amdgcn_s_setprio(1);
#pragma unroll
    for (int m = 0; m < 8; m++)
#pragma unroll
      for (int n = 0; n < 4; n++)
        acc[m][n] = __builtin_amdgcn_mfma_f32_16x16x32_bf16(a[m], b[n], acc[m][n], 0, 0, 0);
    __builtin_amdgcn_s_setprio(0);
    // ---- boundary: next tile's loads must be resident before reads ----
    asm volatile("s_waitcnt vmcnt(0)" ::: "memory");
    __builtin_amdgcn_s_barrier();
    cur ^= 1;
  }
#undef STAGE

  // ---- epilogue ----
  if (MODE == 0) {
    float bcol[4];
#pragma unroll
    for (int n = 0; n < 4; n++) bcol[n] = bias[e * N + n0 + wn * 64 + n * 16 + lr];
#pragma unroll
    for (int m = 0; m < 8; m++)
#pragma unroll
      for (int n = 0; n < 4; n++)
#pragma unroll
        for (int g = 0; g < 4; g++) {
          int row = wm * 128 + m * 16 + kq * 4 + g;
          int col = wn * 64 + n * 16 + lr;
          float v = acc[m][n][g] + bcol[n];
          // tanh-GELU (max abs err ~3e-4 vs erf, well inside bf16 margin)
          float u = v * (0.7978845608f + 0.0356774081f * v * v);
          float gl = v / (1.f + __expf(-2.f * u));
          Hout[(size_t)(r0 + row) * (size_t)N + n0 + col] = f2bf(gl);
        }
  } else {
#pragma unroll
    for (int m = 0; m < 8; m++)
#pragma unroll
      for (int g = 0; g < 4; g++) {
        int row = wm * 128 + m * 16 + kq * 4 + g;
        int tok = sTok[row];
        if (tok >= 0) {
          float p = sP[row];
#pragma unroll
          for (int n = 0; n < 4; n++) {
            int col = wn * 64 + n * 16 + lr;
            atomicAdd(&out[(size_t)tok * DM + n0 + col], p * acc[m][n][g]);
          }
        }
      }
  }
}

// ---------------- launch ----------------

extern "C" void kernel_launch(void* const* d_in, const int* in_sizes, int n_in,
                              void* d_out, int out_size, void* d_ws, size_t ws_size,
                              hipStream_t stream) {
  const float* x  = (const float*)d_in[0];
  const float* rw = (const float*)d_in[1];
  const float* rb = (const float*)d_in[2];
  const float* lw = (const float*)d_in[3];
  const float* lb = (const float*)d_in[4];
  const float* w1 = (const float*)d_in[5];
  const float* b1 = (const float*)d_in[6];
  const float* w2 = (const float*)d_in[7];
  const float* b2 = (const float*)d_in[8];
  float* out = (float*)d_out;
  char* ws = (char*)d_ws;

  int* counts = (int*)ws;
  int* cursor = (int*)(ws + 32);
  int* off    = (int*)(ws + 64);
  int* top_i  = (int*)(ws + 128);                       // 32 KB
  float* top_p = (float*)(ws + 128 + 32768);            // 32 KB
  unsigned* list = (unsigned*)(ws + 128 + 65536);       // 40 KB
  unsigned short* xb = (unsigned short*)(ws + 131072);                      // 8 MB
  unsigned short* wt = (unsigned short*)(ws + 131072 + 8388608);            // 64 MB (shared w1t/w2t)
  unsigned short* h  = (unsigned short*)(ws + 131072 + 8388608 + 67108864); // 80 MB

  k_cvt_init<<<dim3(T_TOK * DM / 4 / 256), dim3(256), 0, stream>>>(x, xb, counts, cursor, list);
  k_route<<<dim3(T_TOK / 4), dim3(256), 0, stream>>>(x, rw, rb, lw, lb, top_i, top_p, counts);
  k_offsets<<<dim3(1), dim3(64), 0, stream>>>(counts, off);
  k_scatter<<<dim3(T_TOK / 256), dim3(256), 0, stream>>>(top_i, off, cursor, list);
  k_transpose_bf16<<<dim3(HS / 64, DM / 64, NE), dim3(256), 0, stream>>>(w1, wt, DM, HS);
  k_init_out<<<dim3(T_TOK * DM / 256), dim3(256), 0, stream>>>(top_i, top_p, b2, out);
  k_gemm<0, DM, HS, DM / 64><<<dim3(HS / 256, MAXTILES, 1), dim3(512), 0, stream>>>(
      xb, wt, off, list, b1, top_p, h, nullptr);
  k_transpose_bf16<<<dim3(DM / 64, HS / 64, NE), dim3(256), 0, stream>>>(w2, wt, HS, DM);
  k_gemm<1, HS, DM, HS / 4 / 64><<<dim3(DM / 256, MAXTILES, 4), dim3(512), 0, stream>>>(
      h, wt, off, list, nullptr, top_p, nullptr, out);
}